// Round 1
// baseline (2664.045 us; speedup 1.0000x reference)
//
#include <hip/hip_runtime.h>
#include <math.h>
#include <float.h>

// Associative memory forward, all fp32 (argmax/softmax fidelity vs np fp32 ref).
// Requires ws_size >= ~29 MB.

#define BATCH 4096
#define CAP   32768
#define KDIM  64
#define SB    8            // slot-blocks (softmax/argmax split)
#define SPB   (CAP/SB)     // 4096 slots per block
#define RB    64           // row-blocks
#define BM    64           // rows per block
#define TS    64           // slots per LDS subtile
#define PAD   68           // float pad for float4-read tiles (68*4B=272B, 16B aligned)

// ---------------- projections: out = tanh(in @ W.T + b) ----------------
__global__ __launch_bounds__(256) void proj_kernel(
    const float* __restrict__ keys, const float* __restrict__ query,
    const float* __restrict__ Wk, const float* __restrict__ bk,
    const float* __restrict__ Wv, const float* __restrict__ bv,
    float* __restrict__ kp, float* __restrict__ sv, float* __restrict__ qp)
{
    int job = blockIdx.y;   // 0: keys->kp (Wk), 1: query->sv (Wv), 2: query->qp (Wk)
    const float* in; const float* W; const float* b; float* out;
    if (job == 0)      { in = keys;  W = Wk; b = bk; out = kp; }
    else if (job == 1) { in = query; W = Wv; b = bv; out = sv; }
    else               { in = query; W = Wk; b = bk; out = qp; }

    __shared__ float Wl[64*65];
    __shared__ float inl[16*65];
    __shared__ float bl[64];
    int tid = threadIdx.x;
    int row0 = blockIdx.x * 16;
    for (int i = tid; i < 4096; i += 256) { int r = i >> 6, c = i & 63; Wl[r*65+c] = W[i]; }
    for (int i = tid; i < 1024; i += 256) { int r = i >> 6, c = i & 63; inl[r*65+c] = in[(row0+r)*64 + c]; }
    if (tid < 64) bl[tid] = b[tid];
    __syncthreads();

    int col = tid & 63;
    int rq  = tid >> 6;       // 0..3
    #pragma unroll
    for (int q = 0; q < 4; ++q) {
        int r = rq*4 + q;     // 0..15
        float acc = bl[col];
        #pragma unroll
        for (int k = 0; k < 64; ++k) acc += inl[r*65+k] * Wl[col*65+k];
        out[(row0+r)*64 + col] = tanhf(acc);
    }
}

// ---------------- sim = kp @ mem_keys.T ; partial argmax ----------------
__global__ __launch_bounds__(256) void sim_argmax_kernel(
    const float* __restrict__ A, const float* __restrict__ Bm,
    float* __restrict__ bestv, int* __restrict__ besti)
{
    __shared__ __align__(16) float Al[BM*PAD];
    __shared__ __align__(16) float Bl[TS*PAD];
    int tid = threadIdx.x;
    int sb = blockIdx.x, rb = blockIdx.y;
    int row0 = rb*BM, slot0 = sb*SPB;

    for (int i = tid; i < BM*KDIM; i += 256) {  // scalar staging: <=2-way LDS banks
        int r = i >> 6, c = i & 63;
        Al[r*PAD + c] = A[(row0+r)*KDIM + c];
    }
    int tx = tid & 15, ty = tid >> 4;
    float bvv[4]; int bii[4];
    #pragma unroll
    for (int i = 0; i < 4; ++i) { bvv[i] = -FLT_MAX; bii[i] = 0; }

    for (int st = 0; st < SPB/TS; ++st) {
        __syncthreads();
        for (int i = tid; i < TS*KDIM; i += 256) {
            int r = i >> 6, c = i & 63;
            Bl[r*PAD + c] = Bm[(slot0 + st*TS + r)*KDIM + c];
        }
        __syncthreads();
        float acc[4][4];
        #pragma unroll
        for (int i = 0; i < 4; ++i)
            #pragma unroll
            for (int j = 0; j < 4; ++j) acc[i][j] = 0.f;
        #pragma unroll
        for (int k = 0; k < KDIM; k += 4) {
            float4 a4[4], b4[4];
            #pragma unroll
            for (int i = 0; i < 4; ++i) a4[i] = *reinterpret_cast<const float4*>(&Al[(ty+i*16)*PAD + k]);
            #pragma unroll
            for (int j = 0; j < 4; ++j) b4[j] = *reinterpret_cast<const float4*>(&Bl[(tx+j*16)*PAD + k]);
            #pragma unroll
            for (int i = 0; i < 4; ++i)
                #pragma unroll
                for (int j = 0; j < 4; ++j)
                    acc[i][j] += a4[i].x*b4[j].x + a4[i].y*b4[j].y + a4[i].z*b4[j].z + a4[i].w*b4[j].w;
        }
        #pragma unroll
        for (int i = 0; i < 4; ++i)
            #pragma unroll
            for (int j = 0; j < 4; ++j) {  // ascending slot order -> first-max kept
                int s = slot0 + st*TS + tx + j*16;
                if (acc[i][j] > bvv[i]) { bvv[i] = acc[i][j]; bii[i] = s; }
            }
    }
    #pragma unroll
    for (int m = 1; m < 16; m <<= 1) {
        #pragma unroll
        for (int i = 0; i < 4; ++i) {
            float ov = __shfl_xor(bvv[i], m);
            int   oi = __shfl_xor(bii[i], m);
            if (ov > bvv[i] || (ov == bvv[i] && oi < bii[i])) { bvv[i] = ov; bii[i] = oi; }
        }
    }
    if (tx == 0) {
        #pragma unroll
        for (int i = 0; i < 4; ++i) {
            int r = row0 + ty + i*16;
            bestv[r*SB + sb] = bvv[i];
            besti[r*SB + sb] = bii[i];
        }
    }
}

// ---------------- argmax combine + winner scatter ----------------
__global__ void argmax_scatter_kernel(const float* __restrict__ bestv,
                                      const int* __restrict__ besti,
                                      int* __restrict__ winner)
{
    int r = blockIdx.x*256 + threadIdx.x;
    if (r >= BATCH) return;
    float bv = bestv[r*SB]; int bi = besti[r*SB];
    #pragma unroll
    for (int sb = 1; sb < SB; ++sb) {
        float v = bestv[r*SB+sb]; int ii = besti[r*SB+sb];
        if (v > bv || (v == bv && ii < bi)) { bv = v; bi = ii; }
    }
    atomicMax(&winner[bi], r);   // last-write-wins == max batch index
}

// ---------------- build new_keys / new_values ----------------
__global__ void build_mem_kernel(const int* __restrict__ winner,
                                 const float* __restrict__ kp, const float* __restrict__ sv,
                                 const float* __restrict__ mk, const float* __restrict__ mv,
                                 float* __restrict__ nk, float* __restrict__ nv)
{
    int idx = blockIdx.x*256 + threadIdx.x;   // CAP*64 total
    int s = idx >> 6, j = idx & 63;
    int w = winner[s];
    nk[idx] = (w >= 0) ? kp[w*64 + j] : mk[idx];
    nv[idx] = (w >= 0) ? sv[w*64 + j] : mv[idx];
}

// ---------------- logits = qp @ nk.T (store raw) + online (m,s) partials ----------------
__global__ __launch_bounds__(256) void logits_kernel(
    const float* __restrict__ A, const float* __restrict__ Bm,
    float* __restrict__ att, float* __restrict__ m_part, float* __restrict__ s_part)
{
    __shared__ __align__(16) float Al[BM*PAD];
    __shared__ __align__(16) float Bl[TS*PAD];
    int tid = threadIdx.x;
    int sb = blockIdx.x, rb = blockIdx.y;
    int row0 = rb*BM, slot0 = sb*SPB;

    for (int i = tid; i < BM*KDIM; i += 256) {
        int r = i >> 6, c = i & 63;
        Al[r*PAD + c] = A[(row0+r)*KDIM + c];
    }
    int tx = tid & 15, ty = tid >> 4;
    float mrun[4], srun[4];
    #pragma unroll
    for (int i = 0; i < 4; ++i) { mrun[i] = -FLT_MAX; srun[i] = 0.f; }

    for (int st = 0; st < SPB/TS; ++st) {
        __syncthreads();
        for (int i = tid; i < TS*KDIM; i += 256) {
            int r = i >> 6, c = i & 63;
            Bl[r*PAD + c] = Bm[(slot0 + st*TS + r)*KDIM + c];
        }
        __syncthreads();
        float acc[4][4];
        #pragma unroll
        for (int i = 0; i < 4; ++i)
            #pragma unroll
            for (int j = 0; j < 4; ++j) acc[i][j] = 0.f;
        #pragma unroll
        for (int k = 0; k < KDIM; k += 4) {
            float4 a4[4], b4[4];
            #pragma unroll
            for (int i = 0; i < 4; ++i) a4[i] = *reinterpret_cast<const float4*>(&Al[(ty+i*16)*PAD + k]);
            #pragma unroll
            for (int j = 0; j < 4; ++j) b4[j] = *reinterpret_cast<const float4*>(&Bl[(tx+j*16)*PAD + k]);
            #pragma unroll
            for (int i = 0; i < 4; ++i)
                #pragma unroll
                for (int j = 0; j < 4; ++j)
                    acc[i][j] += a4[i].x*b4[j].x + a4[i].y*b4[j].y + a4[i].z*b4[j].z + a4[i].w*b4[j].w;
        }
        #pragma unroll
        for (int i = 0; i < 4; ++i)
            #pragma unroll
            for (int j = 0; j < 4; ++j) {
                float v = acc[i][j];
                att[(size_t)(row0 + ty + i*16)*CAP + slot0 + st*TS + tx + j*16] = v;
                if (v <= mrun[i]) { srun[i] += __expf(v - mrun[i]); }
                else { srun[i] = srun[i]*__expf(mrun[i]-v) + 1.f; mrun[i] = v; }
            }
    }
    #pragma unroll
    for (int m = 1; m < 16; m <<= 1) {
        #pragma unroll
        for (int i = 0; i < 4; ++i) {
            float om = __shfl_xor(mrun[i], m);
            float os = __shfl_xor(srun[i], m);
            float Mn = fmaxf(mrun[i], om);
            srun[i] = srun[i]*__expf(mrun[i]-Mn) + os*__expf(om-Mn);
            mrun[i] = Mn;
        }
    }
    if (tx == 0) {
        #pragma unroll
        for (int i = 0; i < 4; ++i) {
            int r = row0 + ty + i*16;
            m_part[r*SB + sb] = mrun[i];
            s_part[r*SB + sb] = srun[i];
        }
    }
}

// ---------------- per-row global softmax stats ----------------
__global__ void stats_combine_kernel(const float* __restrict__ m_part, const float* __restrict__ s_part,
                                     float* __restrict__ Mrow, float* __restrict__ iSrow)
{
    int r = blockIdx.x*256 + threadIdx.x;
    if (r >= BATCH) return;
    float M = -FLT_MAX;
    #pragma unroll
    for (int sb = 0; sb < SB; ++sb) M = fmaxf(M, m_part[r*SB+sb]);
    float S = 0.f;
    #pragma unroll
    for (int sb = 0; sb < SB; ++sb) S += s_part[r*SB+sb]*__expf(m_part[r*SB+sb]-M);
    Mrow[r] = M;
    iSrow[r] = 1.f/S;
}

// ---------------- normalize attention (in-place) + partial retrieved ----------------
__global__ __launch_bounds__(256) void attn_pv_kernel(
    float* __restrict__ att, const float* __restrict__ nv,
    const float* __restrict__ Mrow, const float* __restrict__ iSrow,
    float* __restrict__ ret_part)
{
    __shared__ __align__(16) float Atl[BM*PAD];   // [row][slot], float4 reads
    __shared__ float Vl[TS*65];                   // [slot][v], scalar reads
    __shared__ float Ml[BM], iSl[BM];
    int tid = threadIdx.x;
    int sb = blockIdx.x, rb = blockIdx.y;
    int row0 = rb*BM, slot0 = sb*SPB;
    if (tid < BM) { Ml[tid] = Mrow[row0+tid]; iSl[tid] = iSrow[row0+tid]; }

    int tx = tid & 15, ty = tid >> 4;
    float acc[4][4];
    #pragma unroll
    for (int i = 0; i < 4; ++i)
        #pragma unroll
        for (int j = 0; j < 4; ++j) acc[i][j] = 0.f;

    for (int st = 0; st < SPB/TS; ++st) {
        __syncthreads();
        for (int i = tid; i < BM*TS; i += 256) {
            int r = i >> 6, c = i & 63;
            size_t g = (size_t)(row0+r)*CAP + slot0 + st*TS + c;
            float l = att[g];
            float a = __expf(l - Ml[r]) * iSl[r];
            att[g] = a;
            Atl[r*PAD + c] = a;
        }
        for (int i = tid; i < TS*KDIM; i += 256) {
            int r = i >> 6, c = i & 63;
            Vl[r*65 + c] = nv[(slot0 + st*TS + r)*KDIM + c];
        }
        __syncthreads();
        #pragma unroll
        for (int k = 0; k < TS; k += 4) {
            float4 a4[4];
            #pragma unroll
            for (int i = 0; i < 4; ++i) a4[i] = *reinterpret_cast<const float4*>(&Atl[(ty+i*16)*PAD + k]);
            float bfr[4][4];
            #pragma unroll
            for (int u = 0; u < 4; ++u)
                #pragma unroll
                for (int j = 0; j < 4; ++j) bfr[u][j] = Vl[(k+u)*65 + tx + j*16];
            #pragma unroll
            for (int i = 0; i < 4; ++i)
                #pragma unroll
                for (int j = 0; j < 4; ++j)
                    acc[i][j] += a4[i].x*bfr[0][j] + a4[i].y*bfr[1][j] + a4[i].z*bfr[2][j] + a4[i].w*bfr[3][j];
        }
    }
    #pragma unroll
    for (int i = 0; i < 4; ++i)
        #pragma unroll
        for (int j = 0; j < 4; ++j)
            ret_part[((size_t)sb*BATCH + row0 + ty + i*16)*64 + tx + j*16] = acc[i][j];
}

// ---------------- reduce partial retrieved ----------------
__global__ void ret_reduce_kernel(const float* __restrict__ rp, float* __restrict__ out)
{
    int idx = blockIdx.x*256 + threadIdx.x;   // BATCH*64
    float s = 0.f;
    #pragma unroll
    for (int sb = 0; sb < SB; ++sb) s += rp[(size_t)sb*BATCH*64 + idx];
    out[idx] = s;
}

extern "C" void kernel_launch(void* const* d_in, const int* in_sizes, int n_in,
                              void* d_out, int out_size, void* d_ws, size_t ws_size,
                              hipStream_t stream) {
    const float* keys       = (const float*)d_in[0];
    const float* query      = (const float*)d_in[2];
    const float* mem_keys   = (const float*)d_in[3];
    const float* mem_values = (const float*)d_in[4];
    const float* Wk         = (const float*)d_in[5];
    const float* bk         = (const float*)d_in[6];
    const float* Wv         = (const float*)d_in[7];
    const float* bv         = (const float*)d_in[8];

    float* out = (float*)d_out;
    float* ret = out;                      // [4096,64]
    float* att = out + BATCH*64;           // [4096,32768] (also used as raw-logit scratch)

    float* ws = (float*)d_ws;
    float* kp       = ws;                  // 262144
    float* sv       = ws + 262144;         // 262144
    float* qp       = ws + 524288;         // 262144
    float* nk       = ws + 786432;         // 2097152
    float* nv       = ws + 2883584;        // 2097152
    float* m_part   = ws + 4980736;        // 32768
    float* s_part   = ws + 5013504;        // 32768
    float* Mrow     = ws + 5046272;        // 4096
    float* iSrow    = ws + 5050368;        // 4096
    float* bestv    = ws + 5054464;        // 32768
    float* ret_part = ws + 5087232;        // 2097152
    int*   besti    = (int*)(ws + 7184384);// 32768 ints
    int*   winner   = (int*)(ws + 7217152);// 32768 ints
    // total: 7249920 floats = ~27.7 MB

    hipMemsetAsync(winner, 0xFF, CAP*sizeof(int), stream);   // -1

    proj_kernel<<<dim3(BATCH/16, 3), 256, 0, stream>>>(keys, query, Wk, bk, Wv, bv, kp, sv, qp);
    sim_argmax_kernel<<<dim3(SB, RB), 256, 0, stream>>>(kp, mem_keys, bestv, besti);
    argmax_scatter_kernel<<<BATCH/256, 256, 0, stream>>>(bestv, besti, winner);
    build_mem_kernel<<<CAP*64/256, 256, 0, stream>>>(winner, kp, sv, mem_keys, mem_values, nk, nv);
    logits_kernel<<<dim3(SB, RB), 256, 0, stream>>>(qp, nk, att, m_part, s_part);
    stats_combine_kernel<<<BATCH/256, 256, 0, stream>>>(m_part, s_part, Mrow, iSrow);
    attn_pv_kernel<<<dim3(SB, RB), 256, 0, stream>>>(att, nv, Mrow, iSrow, ret_part);
    ret_reduce_kernel<<<BATCH*64/256, 256, 0, stream>>>(ret_part, ret);
}

// Round 2
// 457.564 us; speedup vs baseline: 5.8222x; 5.8222x over previous
//
#include <hip/hip_runtime.h>
#include <math.h>
#include <float.h>

#define BATCH 4096
#define CAP   32768

typedef _Float16 f16;
typedef _Float16 f16x8 __attribute__((ext_vector_type(8)));
typedef float    f32x4 __attribute__((ext_vector_type(4)));

__device__ __forceinline__ f32x4 MF(f16x8 a, f16x8 b, f32x4 c) {
    return __builtin_amdgcn_mfma_f32_16x16x32_f16(a, b, c, 0, 0, 0);
}

// ---------------- projections: out = tanh(in @ W.T + b), split to f16 planes ----------------
__global__ __launch_bounds__(256) void proj_split_kernel(
    const float* __restrict__ keys, const float* __restrict__ query,
    const float* __restrict__ Wk, const float* __restrict__ bk,
    const float* __restrict__ Wv, const float* __restrict__ bv,
    f16* __restrict__ kph, f16* __restrict__ kpl,
    f16* __restrict__ svh, f16* __restrict__ svl,
    f16* __restrict__ qph, f16* __restrict__ qpl)
{
    int job = blockIdx.y;   // 0: keys@Wk->kp (scaled lo), 1: query@Wv->sv, 2: query@Wk->qp
    const float *in, *W, *b; f16 *oh, *ol; bool scaled;
    if (job == 0)      { in = keys;  W = Wk; b = bk; oh = kph; ol = kpl; scaled = true;  }
    else if (job == 1) { in = query; W = Wv; b = bv; oh = svh; ol = svl; scaled = false; }
    else               { in = query; W = Wk; b = bk; oh = qph; ol = qpl; scaled = false; }

    __shared__ float Wl[64*65];
    __shared__ float inl[16*65];
    __shared__ float bl[64];
    int tid = threadIdx.x;
    int row0 = blockIdx.x * 16;
    for (int i = tid; i < 4096; i += 256) { int r = i >> 6, c = i & 63; Wl[r*65+c] = W[i]; }
    for (int i = tid; i < 1024; i += 256) { int r = i >> 6, c = i & 63; inl[r*65+c] = in[(row0+r)*64 + c]; }
    if (tid < 64) bl[tid] = b[tid];
    __syncthreads();

    int col = tid & 63;
    int rq  = tid >> 6;
    #pragma unroll
    for (int q = 0; q < 4; ++q) {
        int r = rq*4 + q;
        float acc = bl[col];
        #pragma unroll
        for (int k = 0; k < 64; ++k) acc += inl[r*65+k] * Wl[col*65+k];
        float t = tanhf(acc);
        f16 h = (f16)t;
        float lo = t - (float)h;
        if (scaled) lo *= 2048.0f;
        oh[(row0+r)*64 + col] = h;
        ol[(row0+r)*64 + col] = (f16)lo;
    }
}

// ---------------- split mem_keys into scaled f16 planes ----------------
__global__ void split_mk_kernel(const float* __restrict__ mk,
                                f16* __restrict__ mkh, f16* __restrict__ mkl)
{
    int i = blockIdx.x*256 + threadIdx.x;   // CAP*64 threads
    float x = mk[i];
    f16 h = (f16)x;
    mkh[i] = h;
    mkl[i] = (f16)((x - (float)h) * 2048.0f);
}

// ---------------- sim = kp @ mem_keys.T via f16-split MFMA; partial argmax ----------------
// grid (16 sb, 32 rb); block 256 = 4 waves; block tile 128 rows x (2048 slots loop, 64/subtile)
__global__ __launch_bounds__(256) void sim_kernel(
    const f16* __restrict__ Aph, const f16* __restrict__ Apl,
    const f16* __restrict__ Bph, const f16* __restrict__ Bpl,
    float* __restrict__ bestv, int* __restrict__ besti)
{
    __shared__ __align__(16) f16 Bh[64*72], Bl[64*72];
    int tid = threadIdx.x, l = tid & 63, w = tid >> 6;
    int sb = blockIdx.x, rb = blockIdx.y;
    int row0 = rb*128 + w*32;
    int lr = l & 15, lg = l >> 4;

    f16x8 ah[2][2], al[2][2];
    #pragma unroll
    for (int i = 0; i < 2; ++i)
        #pragma unroll
        for (int t = 0; t < 2; ++t) {
            size_t o = (size_t)(row0 + i*16 + lr)*64 + t*32 + lg*8;
            ah[i][t] = *(const f16x8*)&Aph[o];
            al[i][t] = *(const f16x8*)&Apl[o];
        }
    float bvv[2][4]; int bii[2][4];
    #pragma unroll
    for (int i = 0; i < 2; ++i)
        #pragma unroll
        for (int j = 0; j < 4; ++j) { bvv[i][j] = -FLT_MAX; bii[i][j] = 0; }

    for (int st = 0; st < 32; ++st) {
        int s0 = sb*2048 + st*64;
        __syncthreads();
        #pragma unroll
        for (int c = 0; c < 2; ++c) {
            int task = tid + 256*c; int sl = task >> 3, ch = task & 7;
            *(f16x8*)&Bh[sl*72 + ch*8] = *(const f16x8*)&Bph[(size_t)(s0+sl)*64 + ch*8];
            *(f16x8*)&Bl[sl*72 + ch*8] = *(const f16x8*)&Bpl[(size_t)(s0+sl)*64 + ch*8];
        }
        __syncthreads();
        #pragma unroll
        for (int cf = 0; cf < 4; ++cf) {
            int c0 = cf*16;
            f16x8 bh[2], bl2[2];
            #pragma unroll
            for (int t = 0; t < 2; ++t) {
                bh[t]  = *(const f16x8*)&Bh[(c0+lr)*72 + t*32 + lg*8];
                bl2[t] = *(const f16x8*)&Bl[(c0+lr)*72 + t*32 + lg*8];
            }
            f32x4 z = {0.f,0.f,0.f,0.f};
            f32x4 aA[2] = {z, z}, aB[2] = {z, z};
            #pragma unroll
            for (int i = 0; i < 2; ++i)
                #pragma unroll
                for (int t = 0; t < 2; ++t) {
                    aA[i] = MF(ah[i][t], bh[t],  aA[i]);
                    aB[i] = MF(ah[i][t], bl2[t], aB[i]);
                    aB[i] = MF(al[i][t], bh[t],  aB[i]);
                }
            #pragma unroll
            for (int i = 0; i < 2; ++i)
                #pragma unroll
                for (int j = 0; j < 4; ++j) {
                    float v = aA[i][j] + aB[i][j]*(1.0f/2048.0f);
                    int slot = s0 + c0 + lr;
                    if (v > bvv[i][j]) { bvv[i][j] = v; bii[i][j] = slot; }
                }
        }
    }
    #pragma unroll
    for (int m = 1; m < 16; m <<= 1)
        #pragma unroll
        for (int i = 0; i < 2; ++i)
            #pragma unroll
            for (int j = 0; j < 4; ++j) {
                float ov = __shfl_xor(bvv[i][j], m);
                int   oi = __shfl_xor(bii[i][j], m);
                if (ov > bvv[i][j] || (ov == bvv[i][j] && oi < bii[i][j])) { bvv[i][j] = ov; bii[i][j] = oi; }
            }
    if (lr == 0) {
        #pragma unroll
        for (int i = 0; i < 2; ++i)
            #pragma unroll
            for (int j = 0; j < 4; ++j) {
                int r = row0 + i*16 + lg*4 + j;
                bestv[r*16 + sb] = bvv[i][j];
                besti[r*16 + sb] = bii[i][j];
            }
    }
}

// ---------------- argmax combine + winner scatter ----------------
__global__ void argmax_scatter_kernel(const float* __restrict__ bestv,
                                      const int* __restrict__ besti,
                                      int* __restrict__ winner)
{
    int r = blockIdx.x*256 + threadIdx.x;
    if (r >= BATCH) return;
    float bv = bestv[r*16]; int bi = besti[r*16];
    #pragma unroll
    for (int sb = 1; sb < 16; ++sb) {
        float v = bestv[r*16+sb]; int ii = besti[r*16+sb];
        if (v > bv || (v == bv && ii < bi)) { bv = v; bi = ii; }
    }
    atomicMax(&winner[bi], r);
}

// ---------------- build new_keys planes + transposed new_values planes ----------------
__global__ __launch_bounds__(256) void build_kernel(
    const int* __restrict__ winner,
    const f16* __restrict__ kph, const f16* __restrict__ kpl,
    const f16* __restrict__ svh, const f16* __restrict__ svl,
    const float* __restrict__ mk, const float* __restrict__ mv,
    f16* __restrict__ nkh, f16* __restrict__ nkl,
    f16* __restrict__ nvTh, f16* __restrict__ nvTl)
{
    __shared__ __align__(16) f16 Lh[64*72], Ll[64*72];
    int tid = threadIdx.x;
    int s0 = blockIdx.x*64;
    #pragma unroll
    for (int c = 0; c < 2; ++c) {
        int task = tid + 256*c; int sl = task >> 3, ch = task & 7;
        int s = s0 + sl; int w = winner[s];
        f16x8 hk, lk, hv, lv;
        if (w >= 0) {
            hk = *(const f16x8*)&kph[(size_t)w*64 + ch*8];
            f16x8 lraw = *(const f16x8*)&kpl[(size_t)w*64 + ch*8];
            #pragma unroll
            for (int q = 0; q < 8; ++q) lk[q] = (f16)((float)lraw[q] * (1.0f/2048.0f));
            hv = *(const f16x8*)&svh[(size_t)w*64 + ch*8];
            lv = *(const f16x8*)&svl[(size_t)w*64 + ch*8];
        } else {
            #pragma unroll
            for (int q = 0; q < 8; ++q) {
                float x = mk[(size_t)s*64 + ch*8 + q];
                f16 h = (f16)x; hk[q] = h; lk[q] = (f16)(x - (float)h);
                float y = mv[(size_t)s*64 + ch*8 + q];
                f16 h2 = (f16)y; hv[q] = h2; lv[q] = (f16)(y - (float)h2);
            }
        }
        *(f16x8*)&nkh[(size_t)s*64 + ch*8] = hk;
        *(f16x8*)&nkl[(size_t)s*64 + ch*8] = lk;
        *(f16x8*)&Lh[sl*72 + ch*8] = hv;
        *(f16x8*)&Ll[sl*72 + ch*8] = lv;
    }
    __syncthreads();
    int v = tid >> 2, sc = (tid & 3)*16;
    f16x8 a, b2;
    #pragma unroll
    for (int q = 0; q < 8; ++q) { a[q] = Lh[(sc+q)*72 + v]; b2[q] = Lh[(sc+8+q)*72 + v]; }
    *(f16x8*)&nvTh[(size_t)v*CAP + s0 + sc]     = a;
    *(f16x8*)&nvTh[(size_t)v*CAP + s0 + sc + 8] = b2;
    #pragma unroll
    for (int q = 0; q < 8; ++q) { a[q] = Ll[(sc+q)*72 + v]; b2[q] = Ll[(sc+8+q)*72 + v]; }
    *(f16x8*)&nvTl[(size_t)v*CAP + s0 + sc]     = a;
    *(f16x8*)&nvTl[(size_t)v*CAP + s0 + sc + 8] = b2;
}

// ---------------- pass1: logits via MFMA, online (m,s) stats only ----------------
__global__ __launch_bounds__(256) void logits_stats_kernel(
    const f16* __restrict__ Aph, const f16* __restrict__ Apl,
    const f16* __restrict__ Bph, const f16* __restrict__ Bpl,
    float* __restrict__ m_part, float* __restrict__ s_part)
{
    __shared__ __align__(16) f16 Bh[64*72], Bl[64*72];
    int tid = threadIdx.x, l = tid & 63, w = tid >> 6;
    int sb = blockIdx.x, rb = blockIdx.y;
    int row0 = rb*128 + w*32;
    int lr = l & 15, lg = l >> 4;

    f16x8 ah[2][2], al[2][2];
    #pragma unroll
    for (int i = 0; i < 2; ++i)
        #pragma unroll
        for (int t = 0; t < 2; ++t) {
            size_t o = (size_t)(row0 + i*16 + lr)*64 + t*32 + lg*8;
            ah[i][t] = *(const f16x8*)&Aph[o];
            al[i][t] = *(const f16x8*)&Apl[o];
        }
    float mm[2][4], ss[2][4];
    #pragma unroll
    for (int i = 0; i < 2; ++i)
        #pragma unroll
        for (int j = 0; j < 4; ++j) { mm[i][j] = -FLT_MAX; ss[i][j] = 0.f; }

    for (int st = 0; st < 32; ++st) {
        int s0 = sb*2048 + st*64;
        __syncthreads();
        #pragma unroll
        for (int c = 0; c < 2; ++c) {
            int task = tid + 256*c; int sl = task >> 3, ch = task & 7;
            *(f16x8*)&Bh[sl*72 + ch*8] = *(const f16x8*)&Bph[(size_t)(s0+sl)*64 + ch*8];
            *(f16x8*)&Bl[sl*72 + ch*8] = *(const f16x8*)&Bpl[(size_t)(s0+sl)*64 + ch*8];
        }
        __syncthreads();
        #pragma unroll
        for (int cf = 0; cf < 4; ++cf) {
            int c0 = cf*16;
            f16x8 bh[2], bl2[2];
            #pragma unroll
            for (int t = 0; t < 2; ++t) {
                bh[t]  = *(const f16x8*)&Bh[(c0+lr)*72 + t*32 + lg*8];
                bl2[t] = *(const f16x8*)&Bl[(c0+lr)*72 + t*32 + lg*8];
            }
            f32x4 z = {0.f,0.f,0.f,0.f};
            f32x4 acc[2] = {z, z};
            #pragma unroll
            for (int i = 0; i < 2; ++i)
                #pragma unroll
                for (int t = 0; t < 2; ++t) {
                    acc[i] = MF(ah[i][t], bh[t],  acc[i]);
                    acc[i] = MF(ah[i][t], bl2[t], acc[i]);
                    acc[i] = MF(al[i][t], bh[t],  acc[i]);
                }
            #pragma unroll
            for (int i = 0; i < 2; ++i)
                #pragma unroll
                for (int j = 0; j < 4; ++j) {
                    float v = acc[i][j];
                    float Mn = fmaxf(mm[i][j], v);
                    ss[i][j] = ss[i][j]*__expf(mm[i][j]-Mn) + __expf(v-Mn);
                    mm[i][j] = Mn;
                }
        }
    }
    #pragma unroll
    for (int m = 1; m < 16; m <<= 1)
        #pragma unroll
        for (int i = 0; i < 2; ++i)
            #pragma unroll
            for (int j = 0; j < 4; ++j) {
                float om = __shfl_xor(mm[i][j], m);
                float os = __shfl_xor(ss[i][j], m);
                float Mn = fmaxf(mm[i][j], om);
                ss[i][j] = ss[i][j]*__expf(mm[i][j]-Mn) + os*__expf(om-Mn);
                mm[i][j] = Mn;
            }
    if (lr == 0) {
        #pragma unroll
        for (int i = 0; i < 2; ++i)
            #pragma unroll
            for (int j = 0; j < 4; ++j) {
                int r = row0 + i*16 + lg*4 + j;
                m_part[r*16 + sb] = mm[i][j];
                s_part[r*16 + sb] = ss[i][j];
            }
    }
}

// ---------------- combine per-row stats ----------------
__global__ void stats_combine_kernel(const float* __restrict__ m_part, const float* __restrict__ s_part,
                                     float* __restrict__ Mrow, float* __restrict__ iSrow)
{
    int r = blockIdx.x*256 + threadIdx.x;
    if (r >= BATCH) return;
    float M = -FLT_MAX;
    #pragma unroll
    for (int sb = 0; sb < 16; ++sb) M = fmaxf(M, m_part[r*16+sb]);
    float S = 0.f;
    #pragma unroll
    for (int sb = 0; sb < 16; ++sb) S += s_part[r*16+sb]*__expf(m_part[r*16+sb]-M);
    Mrow[r] = M;
    iSrow[r] = 1.f/S;
}

// ---------------- pass2: recompute logits, write att, fused PV ----------------
// grid (8 sb, 64 rb); block 256 = 4 waves in 2x2; block tile 64 rows x (4096 slots loop)
__global__ __launch_bounds__(256) void pass2_kernel(
    const f16* __restrict__ qph, const f16* __restrict__ qpl,
    const f16* __restrict__ nkh, const f16* __restrict__ nkl,
    const f16* __restrict__ nvTh, const f16* __restrict__ nvTl,
    const float* __restrict__ Mrow, const float* __restrict__ iSrow,
    float* __restrict__ att, float* __restrict__ ret_part)
{
    __shared__ __align__(16) f16 Kh[64*72], Kl[64*72];
    __shared__ __align__(16) f16 Ph[64*72], Pl[64*72];
    __shared__ __align__(16) f16 Vh[64*72], Vl[64*72];
    int tid = threadIdx.x, l = tid & 63, w = tid >> 6;
    int wr = w >> 1, wc = w & 1;
    int sb = blockIdx.x, rb = blockIdx.y;
    int row0 = rb*64, wrow0 = row0 + wr*32;
    int lr = l & 15, lg = l >> 4;

    f16x8 ah[2][2], al[2][2];
    #pragma unroll
    for (int i = 0; i < 2; ++i)
        #pragma unroll
        for (int t = 0; t < 2; ++t) {
            size_t o = (size_t)(wrow0 + i*16 + lr)*64 + t*32 + lg*8;
            ah[i][t] = *(const f16x8*)&qph[o];
            al[i][t] = *(const f16x8*)&qpl[o];
        }
    float Ml[2][4], iS[2][4];
    #pragma unroll
    for (int i = 0; i < 2; ++i)
        #pragma unroll
        for (int j = 0; j < 4; ++j) {
            int r = wrow0 + i*16 + lg*4 + j;
            Ml[i][j] = Mrow[r]; iS[i][j] = iSrow[r];
        }
    f32x4 z = {0.f,0.f,0.f,0.f};
    f32x4 pacc[2][2] = {{z,z},{z,z}};

    for (int st = 0; st < 64; ++st) {
        int s0g = sb*4096 + st*64;
        #pragma unroll
        for (int c = 0; c < 2; ++c) {
            int task = tid + 256*c; int sl = task >> 3, ch = task & 7;
            *(f16x8*)&Kh[sl*72 + ch*8] = *(const f16x8*)&nkh[(size_t)(s0g+sl)*64 + ch*8];
            *(f16x8*)&Kl[sl*72 + ch*8] = *(const f16x8*)&nkl[(size_t)(s0g+sl)*64 + ch*8];
        }
        __syncthreads();   // K staged; prev iter's P/V reads are done (barrier C)

        f32x4 qacc[2][2] = {{z,z},{z,z}};
        #pragma unroll
        for (int cf = 0; cf < 2; ++cf) {
            int c0 = wc*32 + cf*16;
            f16x8 bh[2], bl2[2];
            #pragma unroll
            for (int t = 0; t < 2; ++t) {
                bh[t]  = *(const f16x8*)&Kh[(c0+lr)*72 + t*32 + lg*8];
                bl2[t] = *(const f16x8*)&Kl[(c0+lr)*72 + t*32 + lg*8];
            }
            #pragma unroll
            for (int i = 0; i < 2; ++i)
                #pragma unroll
                for (int t = 0; t < 2; ++t) {
                    qacc[i][cf] = MF(ah[i][t], bh[t],  qacc[i][cf]);
                    qacc[i][cf] = MF(ah[i][t], bl2[t], qacc[i][cf]);
                    qacc[i][cf] = MF(al[i][t], bh[t],  qacc[i][cf]);
                }
        }
        #pragma unroll
        for (int i = 0; i < 2; ++i)
            #pragma unroll
            for (int cf = 0; cf < 2; ++cf)
                #pragma unroll
                for (int j = 0; j < 4; ++j) {
                    float v = qacc[i][cf][j];
                    float a = __expf(v - Ml[i][j]) * iS[i][j];
                    int gr = wrow0 + i*16 + lg*4 + j;
                    int gc = s0g + wc*32 + cf*16 + lr;
                    att[(size_t)gr*CAP + gc] = a;
                    int rl = wr*32 + i*16 + lg*4 + j;
                    int cl = wc*32 + cf*16 + lr;
                    f16 h = (f16)a;
                    Ph[rl*72 + cl] = h;
                    Pl[rl*72 + cl] = (f16)(a - (float)h);
                }
        #pragma unroll
        for (int c = 0; c < 2; ++c) {
            int task = tid + 256*c; int vv = task >> 3, ch = task & 7;
            *(f16x8*)&Vh[vv*72 + ch*8] = *(const f16x8*)&nvTh[(size_t)vv*CAP + s0g + ch*8];
            *(f16x8*)&Vl[vv*72 + ch*8] = *(const f16x8*)&nvTl[(size_t)vv*CAP + s0g + ch*8];
        }
        __syncthreads();   // P and V ready

        f16x8 pah[2][2], pal[2][2];
        #pragma unroll
        for (int i = 0; i < 2; ++i)
            #pragma unroll
            for (int t = 0; t < 2; ++t) {
                pah[i][t] = *(const f16x8*)&Ph[(wr*32 + i*16 + lr)*72 + t*32 + lg*8];
                pal[i][t] = *(const f16x8*)&Pl[(wr*32 + i*16 + lr)*72 + t*32 + lg*8];
            }
        #pragma unroll
        for (int vf = 0; vf < 2; ++vf) {
            int c0v = wc*32 + vf*16;
            f16x8 vbh[2], vbl[2];
            #pragma unroll
            for (int t = 0; t < 2; ++t) {
                vbh[t] = *(const f16x8*)&Vh[(c0v+lr)*72 + t*32 + lg*8];
                vbl[t] = *(const f16x8*)&Vl[(c0v+lr)*72 + t*32 + lg*8];
            }
            #pragma unroll
            for (int i = 0; i < 2; ++i)
                #pragma unroll
                for (int t = 0; t < 2; ++t) {
                    pacc[i][vf] = MF(pah[i][t], vbh[t], pacc[i][vf]);
                    pacc[i][vf] = MF(pah[i][t], vbl[t], pacc[i][vf]);
                    pacc[i][vf] = MF(pal[i][t], vbh[t], pacc[i][vf]);
                }
        }
        __syncthreads();   // C: protect P/V/K from next iter's staging
    }
    #pragma unroll
    for (int i = 0; i < 2; ++i)
        #pragma unroll
        for (int vf = 0; vf < 2; ++vf)
            #pragma unroll
            for (int j = 0; j < 4; ++j) {
                int gr = wrow0 + i*16 + lg*4 + j;
                int gc = wc*32 + vf*16 + lr;
                ret_part[((size_t)sb*BATCH + gr)*64 + gc] = pacc[i][vf][j];
            }
}

// ---------------- reduce partial retrieved ----------------
__global__ void ret_reduce_kernel(const float* __restrict__ rp, float* __restrict__ out)
{
    int i4 = blockIdx.x*256 + threadIdx.x;   // BATCH*64/4 = 65536
    float4 s = {0.f,0.f,0.f,0.f};
    #pragma unroll
    for (int sb = 0; sb < 8; ++sb) {
        float4 p = ((const float4*)(rp + (size_t)sb*BATCH*64))[i4];
        s.x += p.x; s.y += p.y; s.z += p.z; s.w += p.w;
    }
    ((float4*)out)[i4] = s;
}

extern "C" void kernel_launch(void* const* d_in, const int* in_sizes, int n_in,
                              void* d_out, int out_size, void* d_ws, size_t ws_size,
                              hipStream_t stream) {
    const float* keys       = (const float*)d_in[0];
    const float* query      = (const float*)d_in[2];
    const float* mem_keys   = (const float*)d_in[3];
    const float* mem_values = (const float*)d_in[4];
    const float* Wk         = (const float*)d_in[5];
    const float* bk         = (const float*)d_in[6];
    const float* Wv         = (const float*)d_in[7];
    const float* bv         = (const float*)d_in[8];

    float* out = (float*)d_out;
    float* ret = out;                       // [4096,64]
    float* att = out + BATCH*64;            // [4096,32768]

    char* ws = (char*)d_ws;
    const size_t SK = (size_t)BATCH*64*2;   // 512 KB  f16 plane [4096][64]
    const size_t SC = (size_t)CAP*64*2;     // 4 MB    f16 plane [32768][64]
    f16* kph  = (f16*)(ws + 0*SK);
    f16* kpl  = (f16*)(ws + 1*SK);
    f16* svh  = (f16*)(ws + 2*SK);
    f16* svl  = (f16*)(ws + 3*SK);
    f16* qph  = (f16*)(ws + 4*SK);
    f16* qpl  = (f16*)(ws + 5*SK);
    size_t o = 6*SK;
    f16* nkh  = (f16*)(ws + o);            o += SC;
    f16* nkl  = (f16*)(ws + o);            o += SC;
    f16* nvTh = (f16*)(ws + o);            o += SC;
    f16* nvTl = (f16*)(ws + o);            o += SC;
    float* bestv  = (float*)(ws + o);      o += (size_t)BATCH*16*4;
    int*   besti  = (int*)(ws + o);        o += (size_t)BATCH*16*4;
    float* m_part = (float*)(ws + o);      o += (size_t)BATCH*16*4;
    float* s_part = (float*)(ws + o);      o += (size_t)BATCH*16*4;
    float* Mrow   = (float*)(ws + o);      o += (size_t)BATCH*4;
    float* iSrow  = (float*)(ws + o);      o += (size_t)BATCH*4;
    int*   winner = (int*)(ws + o);        o += (size_t)CAP*4;
    float* ret_part = (float*)(ws + o);    // 8*4096*64*4 = 8.39 MB
    // mk planes overlaid on ret_part (disjoint lifetimes: sim vs pass2+)
    f16* mkh = (f16*)ret_part;
    f16* mkl = (f16*)((char*)ret_part + SC);

    hipMemsetAsync(winner, 0xFF, CAP*sizeof(int), stream);

    proj_split_kernel<<<dim3(BATCH/16, 3), 256, 0, stream>>>(
        keys, query, Wk, bk, Wv, bv, kph, kpl, svh, svl, qph, qpl);
    split_mk_kernel<<<CAP*64/256, 256, 0, stream>>>(mem_keys, mkh, mkl);
    sim_kernel<<<dim3(16, 32), 256, 0, stream>>>(kph, kpl, mkh, mkl, bestv, besti);
    argmax_scatter_kernel<<<BATCH/256, 256, 0, stream>>>(bestv, besti, winner);
    build_kernel<<<CAP/64, 256, 0, stream>>>(
        winner, kph, kpl, svh, svl, mem_keys, mem_values, nkh, nkl, nvTh, nvTl);
    logits_stats_kernel<<<dim3(16, 32), 256, 0, stream>>>(qph, qpl, nkh, nkl, m_part, s_part);
    stats_combine_kernel<<<BATCH/256, 256, 0, stream>>>(m_part, s_part, Mrow, iSrow);
    pass2_kernel<<<dim3(8, 64), 256, 0, stream>>>(
        qph, qpl, nkh, nkl, nvTh, nvTl, Mrow, iSrow, att, ret_part);
    ret_reduce_kernel<<<BATCH*64/4/256, 256, 0, stream>>>(ret_part, ret);
}

// Round 3
// 381.670 us; speedup vs baseline: 6.9800x; 1.1988x over previous
//
#include <hip/hip_runtime.h>
#include <math.h>
#include <float.h>

#define BATCH 4096
#define CAP   32768

typedef _Float16 f16;
typedef _Float16 f16x8 __attribute__((ext_vector_type(8)));
typedef float    f32x4 __attribute__((ext_vector_type(4)));

__device__ __forceinline__ f32x4 MF(f16x8 a, f16x8 b, f32x4 c) {
    return __builtin_amdgcn_mfma_f32_16x16x32_f16(a, b, c, 0, 0, 0);
}

// ---------------- projections: out = tanh(in @ W.T + b), split to f16 planes ----------------
__global__ __launch_bounds__(256) void proj_split_kernel(
    const float* __restrict__ keys, const float* __restrict__ query,
    const float* __restrict__ Wk, const float* __restrict__ bk,
    const float* __restrict__ Wv, const float* __restrict__ bv,
    f16* __restrict__ kph, f16* __restrict__ kpl,
    f16* __restrict__ svh,
    f16* __restrict__ qph, f16* __restrict__ qpl)
{
    int job = blockIdx.y;   // 0: keys@Wk->kp (scaled lo), 1: query@Wv->sv (hi only), 2: query@Wk->qp
    const float *in, *W, *b; f16 *oh, *ol; bool scaled;
    if (job == 0)      { in = keys;  W = Wk; b = bk; oh = kph; ol = kpl;     scaled = true;  }
    else if (job == 1) { in = query; W = Wv; b = bv; oh = svh; ol = nullptr; scaled = false; }
    else               { in = query; W = Wk; b = bk; oh = qph; ol = qpl;     scaled = false; }

    __shared__ float Wl[64*65];
    __shared__ float inl[16*65];
    __shared__ float bl[64];
    int tid = threadIdx.x;
    int row0 = blockIdx.x * 16;
    for (int i = tid; i < 4096; i += 256) { int r = i >> 6, c = i & 63; Wl[r*65+c] = W[i]; }
    for (int i = tid; i < 1024; i += 256) { int r = i >> 6, c = i & 63; inl[r*65+c] = in[(row0+r)*64 + c]; }
    if (tid < 64) bl[tid] = b[tid];
    __syncthreads();

    int col = tid & 63;
    int rq  = tid >> 6;
    #pragma unroll
    for (int q = 0; q < 4; ++q) {
        int r = rq*4 + q;
        float acc = bl[col];
        #pragma unroll
        for (int k = 0; k < 64; ++k) acc += inl[r*65+k] * Wl[col*65+k];
        float t = tanhf(acc);
        f16 h = (f16)t;
        oh[(row0+r)*64 + col] = h;
        if (ol) {
            float lo = t - (float)h;
            if (scaled) lo *= 2048.0f;
            ol[(row0+r)*64 + col] = (f16)lo;
        }
    }
}

// ---------------- split mem_keys into scaled f16 planes + winner init ----------------
__global__ void split_mk_kernel(const float* __restrict__ mk,
                                f16* __restrict__ mkh, f16* __restrict__ mkl,
                                int* __restrict__ winner)
{
    int i = blockIdx.x*256 + threadIdx.x;   // CAP*64 threads
    float x = mk[i];
    f16 h = (f16)x;
    mkh[i] = h;
    mkl[i] = (f16)((x - (float)h) * 2048.0f);
    if (i < CAP) winner[i] = -1;
}

// ---------------- sim = kp @ mem_keys.T via f16-split MFMA; partial argmax ----------------
// grid (32 sb x 1024 slots, 16 rb x 256 rows); block 256 = 4 waves x 64 rows
__global__ __launch_bounds__(256, 2) void sim_kernel(
    const f16* __restrict__ Aph, const f16* __restrict__ Apl,
    const f16* __restrict__ Bph, const f16* __restrict__ Bpl,
    float* __restrict__ bestv, int* __restrict__ besti)
{
    __shared__ __align__(16) f16 Bh[64*72], Bl[64*72];
    int tid = threadIdx.x, l = tid & 63, w = tid >> 6;
    int sb = blockIdx.x, rb = blockIdx.y;
    int row0 = rb*256 + w*64;
    int lr = l & 15, lg = l >> 4;
    int sl0 = tid >> 3, ch = tid & 7;

    f16x8 ah[4][2], al[4][2];
    #pragma unroll
    for (int i = 0; i < 4; ++i)
        #pragma unroll
        for (int t = 0; t < 2; ++t) {
            size_t o = (size_t)(row0 + i*16 + lr)*64 + t*32 + lg*8;
            ah[i][t] = *(const f16x8*)&Aph[o];
            al[i][t] = *(const f16x8*)&Apl[o];
        }
    float bvv[4][4]; int bii[4][4];
    #pragma unroll
    for (int i = 0; i < 4; ++i)
        #pragma unroll
        for (int j = 0; j < 4; ++j) { bvv[i][j] = -FLT_MAX; bii[i][j] = 0; }

    // prefetch tile 0
    f16x8 pb[2][2];
    {
        int s0 = sb*1024;
        pb[0][0] = *(const f16x8*)&Bph[(size_t)(s0+sl0)*64 + ch*8];
        pb[0][1] = *(const f16x8*)&Bpl[(size_t)(s0+sl0)*64 + ch*8];
        pb[1][0] = *(const f16x8*)&Bph[(size_t)(s0+sl0+32)*64 + ch*8];
        pb[1][1] = *(const f16x8*)&Bpl[(size_t)(s0+sl0+32)*64 + ch*8];
    }

    for (int st = 0; st < 16; ++st) {
        int s0 = sb*1024 + st*64;
        __syncthreads();
        *(f16x8*)&Bh[sl0*72 + ch*8]      = pb[0][0];
        *(f16x8*)&Bl[sl0*72 + ch*8]      = pb[0][1];
        *(f16x8*)&Bh[(sl0+32)*72 + ch*8] = pb[1][0];
        *(f16x8*)&Bl[(sl0+32)*72 + ch*8] = pb[1][1];
        __syncthreads();
        if (st + 1 < 16) {   // issue next tile's loads; hide under MFMA
            int sn = s0 + 64;
            pb[0][0] = *(const f16x8*)&Bph[(size_t)(sn+sl0)*64 + ch*8];
            pb[0][1] = *(const f16x8*)&Bpl[(size_t)(sn+sl0)*64 + ch*8];
            pb[1][0] = *(const f16x8*)&Bph[(size_t)(sn+sl0+32)*64 + ch*8];
            pb[1][1] = *(const f16x8*)&Bpl[(size_t)(sn+sl0+32)*64 + ch*8];
        }
        #pragma unroll
        for (int cf = 0; cf < 4; ++cf) {
            int c0 = cf*16;
            f16x8 bh[2], bl2[2];
            #pragma unroll
            for (int t = 0; t < 2; ++t) {
                bh[t]  = *(const f16x8*)&Bh[(c0+lr)*72 + t*32 + lg*8];
                bl2[t] = *(const f16x8*)&Bl[(c0+lr)*72 + t*32 + lg*8];
            }
            f32x4 z = {0.f,0.f,0.f,0.f};
            f32x4 aA[4] = {z,z,z,z}, aB[4] = {z,z,z,z};
            #pragma unroll
            for (int i = 0; i < 4; ++i)
                #pragma unroll
                for (int t = 0; t < 2; ++t) {
                    aA[i] = MF(ah[i][t], bh[t],  aA[i]);
                    aB[i] = MF(ah[i][t], bl2[t], aB[i]);
                    aB[i] = MF(al[i][t], bh[t],  aB[i]);
                }
            int slot = s0 + c0 + lr;
            #pragma unroll
            for (int i = 0; i < 4; ++i)
                #pragma unroll
                for (int j = 0; j < 4; ++j) {
                    float v = aA[i][j] + aB[i][j]*(1.0f/2048.0f);
                    if (v > bvv[i][j]) { bvv[i][j] = v; bii[i][j] = slot; }
                }
        }
    }
    #pragma unroll
    for (int m = 1; m < 16; m <<= 1)
        #pragma unroll
        for (int i = 0; i < 4; ++i)
            #pragma unroll
            for (int j = 0; j < 4; ++j) {
                float ov = __shfl_xor(bvv[i][j], m);
                int   oi = __shfl_xor(bii[i][j], m);
                if (ov > bvv[i][j] || (ov == bvv[i][j] && oi < bii[i][j])) { bvv[i][j] = ov; bii[i][j] = oi; }
            }
    if (lr == 0) {
        #pragma unroll
        for (int i = 0; i < 4; ++i)
            #pragma unroll
            for (int j = 0; j < 4; ++j) {
                int r = row0 + i*16 + lg*4 + j;
                bestv[r*32 + sb] = bvv[i][j];
                besti[r*32 + sb] = bii[i][j];
            }
    }
}

// ---------------- argmax combine + winner scatter ----------------
__global__ void argmax_scatter_kernel(const float* __restrict__ bestv,
                                      const int* __restrict__ besti,
                                      int* __restrict__ winner)
{
    int r = blockIdx.x*256 + threadIdx.x;
    if (r >= BATCH) return;
    float bv = bestv[r*32]; int bi = besti[r*32];
    #pragma unroll
    for (int sb = 1; sb < 32; ++sb) {
        float v = bestv[r*32+sb]; int ii = besti[r*32+sb];
        if (v > bv || (v == bv && ii < bi)) { bv = v; bi = ii; }
    }
    atomicMax(&winner[bi], r);
}

// ---------------- build new_keys planes + transposed new_values (hi only) ----------------
__global__ __launch_bounds__(256) void build_kernel(
    const int* __restrict__ winner,
    const f16* __restrict__ kph, const f16* __restrict__ kpl,
    const f16* __restrict__ svh,
    const float* __restrict__ mk, const float* __restrict__ mv,
    f16* __restrict__ nkh, f16* __restrict__ nkl,
    f16* __restrict__ nvTh)
{
    __shared__ __align__(16) f16 Lh[64*72];
    int tid = threadIdx.x;
    int s0 = blockIdx.x*64;
    #pragma unroll
    for (int c = 0; c < 2; ++c) {
        int task = tid + 256*c; int sl = task >> 3, ch = task & 7;
        int s = s0 + sl; int w = winner[s];
        f16x8 hk, lk, hv;
        if (w >= 0) {
            hk = *(const f16x8*)&kph[(size_t)w*64 + ch*8];
            f16x8 lraw = *(const f16x8*)&kpl[(size_t)w*64 + ch*8];
            #pragma unroll
            for (int q = 0; q < 8; ++q) lk[q] = (f16)((float)lraw[q] * (1.0f/2048.0f));
            hv = *(const f16x8*)&svh[(size_t)w*64 + ch*8];
        } else {
            #pragma unroll
            for (int q = 0; q < 8; ++q) {
                float x = mk[(size_t)s*64 + ch*8 + q];
                f16 h = (f16)x; hk[q] = h; lk[q] = (f16)(x - (float)h);
                float y = mv[(size_t)s*64 + ch*8 + q];
                hv[q] = (f16)y;
            }
        }
        *(f16x8*)&nkh[(size_t)s*64 + ch*8] = hk;
        *(f16x8*)&nkl[(size_t)s*64 + ch*8] = lk;
        *(f16x8*)&Lh[sl*72 + ch*8] = hv;
    }
    __syncthreads();
    int v = tid >> 2, sc = (tid & 3)*16;
    f16x8 a, b2;
    #pragma unroll
    for (int q = 0; q < 8; ++q) { a[q] = Lh[(sc+q)*72 + v]; b2[q] = Lh[(sc+8+q)*72 + v]; }
    *(f16x8*)&nvTh[(size_t)v*CAP + s0 + sc]     = a;
    *(f16x8*)&nvTh[(size_t)v*CAP + s0 + sc + 8] = b2;
}

// ---------------- pass1: logits via MFMA, online (m,s) stats only ----------------
// grid (32 sb, 16 rb); block 256 = 4 waves x 64 rows
__global__ __launch_bounds__(256, 2) void logits_stats_kernel(
    const f16* __restrict__ Aph, const f16* __restrict__ Apl,
    const f16* __restrict__ Bph, const f16* __restrict__ Bpl,
    float* __restrict__ m_part, float* __restrict__ s_part)
{
    __shared__ __align__(16) f16 Bh[64*72], Bl[64*72];
    int tid = threadIdx.x, l = tid & 63, w = tid >> 6;
    int sb = blockIdx.x, rb = blockIdx.y;
    int row0 = rb*256 + w*64;
    int lr = l & 15, lg = l >> 4;
    int sl0 = tid >> 3, ch = tid & 7;

    f16x8 ah[4][2], al[4][2];
    #pragma unroll
    for (int i = 0; i < 4; ++i)
        #pragma unroll
        for (int t = 0; t < 2; ++t) {
            size_t o = (size_t)(row0 + i*16 + lr)*64 + t*32 + lg*8;
            ah[i][t] = *(const f16x8*)&Aph[o];
            al[i][t] = *(const f16x8*)&Apl[o];
        }
    float mm[4][4], ss[4][4];
    #pragma unroll
    for (int i = 0; i < 4; ++i)
        #pragma unroll
        for (int j = 0; j < 4; ++j) { mm[i][j] = -FLT_MAX; ss[i][j] = 0.f; }

    f16x8 pb[2][2];
    {
        int s0 = sb*1024;
        pb[0][0] = *(const f16x8*)&Bph[(size_t)(s0+sl0)*64 + ch*8];
        pb[0][1] = *(const f16x8*)&Bpl[(size_t)(s0+sl0)*64 + ch*8];
        pb[1][0] = *(const f16x8*)&Bph[(size_t)(s0+sl0+32)*64 + ch*8];
        pb[1][1] = *(const f16x8*)&Bpl[(size_t)(s0+sl0+32)*64 + ch*8];
    }

    for (int st = 0; st < 16; ++st) {
        int s0 = sb*1024 + st*64;
        __syncthreads();
        *(f16x8*)&Bh[sl0*72 + ch*8]      = pb[0][0];
        *(f16x8*)&Bl[sl0*72 + ch*8]      = pb[0][1];
        *(f16x8*)&Bh[(sl0+32)*72 + ch*8] = pb[1][0];
        *(f16x8*)&Bl[(sl0+32)*72 + ch*8] = pb[1][1];
        __syncthreads();
        if (st + 1 < 16) {
            int sn = s0 + 64;
            pb[0][0] = *(const f16x8*)&Bph[(size_t)(sn+sl0)*64 + ch*8];
            pb[0][1] = *(const f16x8*)&Bpl[(size_t)(sn+sl0)*64 + ch*8];
            pb[1][0] = *(const f16x8*)&Bph[(size_t)(sn+sl0+32)*64 + ch*8];
            pb[1][1] = *(const f16x8*)&Bpl[(size_t)(sn+sl0+32)*64 + ch*8];
        }
        #pragma unroll
        for (int cf = 0; cf < 4; ++cf) {
            int c0 = cf*16;
            f16x8 bh[2], bl2[2];
            #pragma unroll
            for (int t = 0; t < 2; ++t) {
                bh[t]  = *(const f16x8*)&Bh[(c0+lr)*72 + t*32 + lg*8];
                bl2[t] = *(const f16x8*)&Bl[(c0+lr)*72 + t*32 + lg*8];
            }
            f32x4 z = {0.f,0.f,0.f,0.f};
            f32x4 acc[4] = {z,z,z,z};
            #pragma unroll
            for (int i = 0; i < 4; ++i)
                #pragma unroll
                for (int t = 0; t < 2; ++t) {
                    acc[i] = MF(ah[i][t], bh[t],  acc[i]);
                    acc[i] = MF(ah[i][t], bl2[t], acc[i]);
                    acc[i] = MF(al[i][t], bh[t],  acc[i]);
                }
            #pragma unroll
            for (int i = 0; i < 4; ++i)
                #pragma unroll
                for (int j = 0; j < 4; ++j) {
                    float v = acc[i][j];
                    float d = v - mm[i][j];
                    float e = __expf(-fabsf(d));       // 1-exp online update
                    ss[i][j] = (d > 0.f) ? ss[i][j]*e + 1.f : ss[i][j] + e;
                    mm[i][j] = fmaxf(mm[i][j], v);
                }
        }
    }
    #pragma unroll
    for (int m = 1; m < 16; m <<= 1)
        #pragma unroll
        for (int i = 0; i < 4; ++i)
            #pragma unroll
            for (int j = 0; j < 4; ++j) {
                float om = __shfl_xor(mm[i][j], m);
                float os = __shfl_xor(ss[i][j], m);
                float Mn = fmaxf(mm[i][j], om);
                ss[i][j] = ss[i][j]*__expf(mm[i][j]-Mn) + os*__expf(om-Mn);
                mm[i][j] = Mn;
            }
    if (lr == 0) {
        #pragma unroll
        for (int i = 0; i < 4; ++i)
            #pragma unroll
            for (int j = 0; j < 4; ++j) {
                int r = row0 + i*16 + lg*4 + j;
                m_part[r*32 + sb] = mm[i][j];
                s_part[r*32 + sb] = ss[i][j];
            }
    }
}

// ---------------- combine per-row stats ----------------
__global__ void stats_combine_kernel(const float* __restrict__ m_part, const float* __restrict__ s_part,
                                     float* __restrict__ Mrow, float* __restrict__ iSrow)
{
    int r = blockIdx.x*256 + threadIdx.x;
    if (r >= BATCH) return;
    float M = -FLT_MAX;
    #pragma unroll
    for (int sb = 0; sb < 32; ++sb) M = fmaxf(M, m_part[r*32+sb]);
    float S = 0.f;
    #pragma unroll
    for (int sb = 0; sb < 32; ++sb) S += s_part[r*32+sb]*__expf(m_part[r*32+sb]-M);
    Mrow[r] = M;
    iSrow[r] = 1.f/S;
}

// ---------------- pass2: recompute logits (3-term), write att, fused PV (1-term) ----------------
// grid (16 sb x 2048 slots, 32 rb x 128 rows); block 256 = 4 waves (2 wr x 2 wc), wave = 64 rows x 32 cols
__global__ __launch_bounds__(256, 2) void pass2_kernel(
    const f16* __restrict__ qph, const f16* __restrict__ qpl,
    const f16* __restrict__ nkh, const f16* __restrict__ nkl,
    const f16* __restrict__ nvTh,
    const float* __restrict__ Mrow, const float* __restrict__ iSrow,
    float* __restrict__ att, float* __restrict__ ret_part)
{
    __shared__ __align__(16) f16 Kh[64*72], Kl[64*72];
    __shared__ __align__(16) f16 Vh[64*72];
    __shared__ __align__(16) f16 Ph[128*72];
    int tid = threadIdx.x, l = tid & 63, w = tid >> 6;
    int wr = w >> 1, wc = w & 1;
    int sb = blockIdx.x, rb = blockIdx.y;
    int wrow0 = rb*128 + wr*64;
    int lr = l & 15, lg = l >> 4;
    int sl0 = tid >> 3, ch = tid & 7;

    f16x8 ah[4][2], al[4][2];
    #pragma unroll
    for (int i = 0; i < 4; ++i)
        #pragma unroll
        for (int t = 0; t < 2; ++t) {
            size_t o = (size_t)(wrow0 + i*16 + lr)*64 + t*32 + lg*8;
            ah[i][t] = *(const f16x8*)&qph[o];
            al[i][t] = *(const f16x8*)&qpl[o];
        }
    float Ml[4][4], iS[4][4];
    #pragma unroll
    for (int i = 0; i < 4; ++i)
        #pragma unroll
        for (int j = 0; j < 4; ++j) {
            int r = wrow0 + i*16 + lg*4 + j;
            Ml[i][j] = Mrow[r]; iS[i][j] = iSrow[r];
        }
    f32x4 z = {0.f,0.f,0.f,0.f};
    f32x4 pacc[4][2] = {{z,z},{z,z},{z,z},{z,z}};   // [i][vf]

    f16x8 pk[2][2], pv[2];
    {
        int s0g = sb*2048;
        pk[0][0] = *(const f16x8*)&nkh[(size_t)(s0g+sl0)*64 + ch*8];
        pk[0][1] = *(const f16x8*)&nkl[(size_t)(s0g+sl0)*64 + ch*8];
        pk[1][0] = *(const f16x8*)&nkh[(size_t)(s0g+sl0+32)*64 + ch*8];
        pk[1][1] = *(const f16x8*)&nkl[(size_t)(s0g+sl0+32)*64 + ch*8];
        pv[0]    = *(const f16x8*)&nvTh[(size_t)sl0*CAP + s0g + ch*8];
        pv[1]    = *(const f16x8*)&nvTh[(size_t)(sl0+32)*CAP + s0g + ch*8];
    }

    for (int st = 0; st < 32; ++st) {
        int s0g = sb*2048 + st*64;
        __syncthreads();   // prev tile's reads done; LDS free
        *(f16x8*)&Kh[sl0*72 + ch*8]      = pk[0][0];
        *(f16x8*)&Kl[sl0*72 + ch*8]      = pk[0][1];
        *(f16x8*)&Kh[(sl0+32)*72 + ch*8] = pk[1][0];
        *(f16x8*)&Kl[(sl0+32)*72 + ch*8] = pk[1][1];
        *(f16x8*)&Vh[sl0*72 + ch*8]      = pv[0];
        *(f16x8*)&Vh[(sl0+32)*72 + ch*8] = pv[1];
        __syncthreads();
        if (st + 1 < 32) {
            int sn = s0g + 64;
            pk[0][0] = *(const f16x8*)&nkh[(size_t)(sn+sl0)*64 + ch*8];
            pk[0][1] = *(const f16x8*)&nkl[(size_t)(sn+sl0)*64 + ch*8];
            pk[1][0] = *(const f16x8*)&nkh[(size_t)(sn+sl0+32)*64 + ch*8];
            pk[1][1] = *(const f16x8*)&nkl[(size_t)(sn+sl0+32)*64 + ch*8];
            pv[0]    = *(const f16x8*)&nvTh[(size_t)sl0*CAP + sn + ch*8];
            pv[1]    = *(const f16x8*)&nvTh[(size_t)(sl0+32)*CAP + sn + ch*8];
        }
        // QK^T (3-term) + att write + P to LDS
        #pragma unroll
        for (int cf = 0; cf < 2; ++cf) {
            int c0 = wc*32 + cf*16;
            f16x8 bh[2], bl2[2];
            #pragma unroll
            for (int t = 0; t < 2; ++t) {
                bh[t]  = *(const f16x8*)&Kh[(c0+lr)*72 + t*32 + lg*8];
                bl2[t] = *(const f16x8*)&Kl[(c0+lr)*72 + t*32 + lg*8];
            }
            f32x4 qacc[4] = {z,z,z,z};
            #pragma unroll
            for (int i = 0; i < 4; ++i)
                #pragma unroll
                for (int t = 0; t < 2; ++t) {
                    qacc[i] = MF(ah[i][t], bh[t],  qacc[i]);
                    qacc[i] = MF(ah[i][t], bl2[t], qacc[i]);
                    qacc[i] = MF(al[i][t], bh[t],  qacc[i]);
                }
            #pragma unroll
            for (int i = 0; i < 4; ++i)
                #pragma unroll
                for (int j = 0; j < 4; ++j) {
                    float a = __expf(qacc[i][j] - Ml[i][j]) * iS[i][j];
                    int gr = wrow0 + i*16 + lg*4 + j;
                    att[(size_t)gr*CAP + s0g + c0 + lr] = a;
                    Ph[(wr*64 + i*16 + lg*4 + j)*72 + c0 + lr] = (f16)a;
                }
        }
        __syncthreads();   // P visible
        // PV (1-term)
        f16x8 pah[4][2];
        #pragma unroll
        for (int i = 0; i < 4; ++i)
            #pragma unroll
            for (int t = 0; t < 2; ++t)
                pah[i][t] = *(const f16x8*)&Ph[(wr*64 + i*16 + lr)*72 + t*32 + lg*8];
        #pragma unroll
        for (int vf = 0; vf < 2; ++vf) {
            f16x8 vbh[2];
            #pragma unroll
            for (int t = 0; t < 2; ++t)
                vbh[t] = *(const f16x8*)&Vh[(wc*32 + vf*16 + lr)*72 + t*32 + lg*8];
            #pragma unroll
            for (int i = 0; i < 4; ++i)
                #pragma unroll
                for (int t = 0; t < 2; ++t)
                    pacc[i][vf] = MF(pah[i][t], vbh[t], pacc[i][vf]);
        }
    }
    #pragma unroll
    for (int i = 0; i < 4; ++i)
        #pragma unroll
        for (int vf = 0; vf < 2; ++vf)
            #pragma unroll
            for (int j = 0; j < 4; ++j) {
                int gr = wrow0 + i*16 + lg*4 + j;
                int gc = wc*32 + vf*16 + lr;
                ret_part[((size_t)sb*BATCH + gr)*64 + gc] = pacc[i][vf][j];
            }
}

// ---------------- reduce partial retrieved ----------------
__global__ void ret_reduce_kernel(const float* __restrict__ rp, float* __restrict__ out)
{
    int i4 = blockIdx.x*256 + threadIdx.x;   // BATCH*64/4 = 65536
    float4 s = {0.f,0.f,0.f,0.f};
    #pragma unroll
    for (int sb = 0; sb < 16; ++sb) {
        float4 p = ((const float4*)(rp + (size_t)sb*BATCH*64))[i4];
        s.x += p.x; s.y += p.y; s.z += p.z; s.w += p.w;
    }
    ((float4*)out)[i4] = s;
}

extern "C" void kernel_launch(void* const* d_in, const int* in_sizes, int n_in,
                              void* d_out, int out_size, void* d_ws, size_t ws_size,
                              hipStream_t stream) {
    const float* keys       = (const float*)d_in[0];
    const float* query      = (const float*)d_in[2];
    const float* mem_keys   = (const float*)d_in[3];
    const float* mem_values = (const float*)d_in[4];
    const float* Wk         = (const float*)d_in[5];
    const float* bk         = (const float*)d_in[6];
    const float* Wv         = (const float*)d_in[7];
    const float* bv         = (const float*)d_in[8];

    float* out = (float*)d_out;
    float* ret = out;                       // [4096,64]
    float* att = out + BATCH*64;            // [4096,32768]

    char* ws = (char*)d_ws;
    const size_t SK = (size_t)BATCH*64*2;   // 512 KB  f16 plane [4096][64]
    const size_t SC = (size_t)CAP*64*2;     // 4 MB    f16 plane [32768][64]
    f16* kph  = (f16*)(ws + 0*SK);
    f16* kpl  = (f16*)(ws + 1*SK);
    f16* svh  = (f16*)(ws + 2*SK);
    f16* qph  = (f16*)(ws + 3*SK);
    f16* qpl  = (f16*)(ws + 4*SK);
    size_t o = 5*SK;
    f16* nkh  = (f16*)(ws + o);            o += SC;
    f16* nkl  = (f16*)(ws + o);            o += SC;
    f16* nvTh = (f16*)(ws + o);            o += SC;
    float* bestv  = (float*)(ws + o);      o += (size_t)BATCH*32*4;
    int*   besti  = (int*)(ws + o);        o += (size_t)BATCH*32*4;
    float* m_part = (float*)(ws + o);      o += (size_t)BATCH*32*4;
    float* s_part = (float*)(ws + o);      o += (size_t)BATCH*32*4;
    float* Mrow   = (float*)(ws + o);      o += (size_t)BATCH*4;
    float* iSrow  = (float*)(ws + o);      o += (size_t)BATCH*4;
    int*   winner = (int*)(ws + o);        o += (size_t)CAP*4;
    float* ret_part = (float*)(ws + o);    // 16*4096*64*4 = 16.8 MB
    // mk planes overlaid on ret_part (disjoint lifetimes: sim vs pass2)
    f16* mkh = (f16*)ret_part;
    f16* mkl = (f16*)((char*)ret_part + SC);

    proj_split_kernel<<<dim3(BATCH/16, 3), 256, 0, stream>>>(
        keys, query, Wk, bk, Wv, bv, kph, kpl, svh, qph, qpl);
    split_mk_kernel<<<CAP*64/256, 256, 0, stream>>>(mem_keys, mkh, mkl, winner);
    sim_kernel<<<dim3(32, 16), 256, 0, stream>>>(kph, kpl, mkh, mkl, bestv, besti);
    argmax_scatter_kernel<<<BATCH/256, 256, 0, stream>>>(bestv, besti, winner);
    build_kernel<<<CAP/64, 256, 0, stream>>>(
        winner, kph, kpl, svh, mem_keys, mem_values, nkh, nkl, nvTh);
    logits_stats_kernel<<<dim3(32, 16), 256, 0, stream>>>(qph, qpl, nkh, nkl, m_part, s_part);
    stats_combine_kernel<<<BATCH/256, 256, 0, stream>>>(m_part, s_part, Mrow, iSrow);
    pass2_kernel<<<dim3(16, 32), 256, 0, stream>>>(
        qph, qpl, nkh, nkl, nvTh, Mrow, iSrow, att, ret_part);
    ret_reduce_kernel<<<BATCH*64/4/256, 256, 0, stream>>>(ret_part, ret);
}

// Round 4
// 367.405 us; speedup vs baseline: 7.2510x; 1.0388x over previous
//
#include <hip/hip_runtime.h>
#include <math.h>
#include <float.h>

#define BATCH 4096
#define CAP   32768

typedef _Float16 f16;
typedef _Float16 f16x8 __attribute__((ext_vector_type(8)));
typedef float    f32x4 __attribute__((ext_vector_type(4)));

__device__ __forceinline__ f32x4 MF(f16x8 a, f16x8 b, f32x4 c) {
    return __builtin_amdgcn_mfma_f32_16x16x32_f16(a, b, c, 0, 0, 0);
}

// ---------------- fused prep: projections + mem_keys split + winner init ----------------
// blocks [0,768): proj jobs; blocks [768, 768+8192): split mem_keys / init winner
__global__ __launch_bounds__(256) void prep_kernel(
    const float* __restrict__ keys, const float* __restrict__ query,
    const float* __restrict__ Wk, const float* __restrict__ bk,
    const float* __restrict__ Wv, const float* __restrict__ bv,
    const float* __restrict__ mk,
    f16* __restrict__ kph, f16* __restrict__ kpl,
    f16* __restrict__ svh,
    f16* __restrict__ qph, f16* __restrict__ qpl,
    f16* __restrict__ mkh, f16* __restrict__ mkl,
    int* __restrict__ winner)
{
    int bx = blockIdx.x;
    int tid = threadIdx.x;
    if (bx >= 768) {
        int i = (bx - 768)*256 + tid;    // CAP*64 elements
        float x = mk[i];
        f16 h = (f16)x;
        mkh[i] = h;
        mkl[i] = (f16)((x - (float)h) * 2048.0f);
        if (i < CAP) winner[i] = -1;
        return;
    }
    int job = bx >> 8;   // 0: keys@Wk->kp (scaled lo), 1: query@Wv->sv (hi only), 2: query@Wk->qp
    const float *in, *W, *b; f16 *oh, *ol; bool scaled;
    if (job == 0)      { in = keys;  W = Wk; b = bk; oh = kph; ol = kpl;     scaled = true;  }
    else if (job == 1) { in = query; W = Wv; b = bv; oh = svh; ol = nullptr; scaled = false; }
    else               { in = query; W = Wk; b = bk; oh = qph; ol = qpl;     scaled = false; }

    __shared__ float Wl[64*65];
    __shared__ float inl[16*65];
    __shared__ float bl[64];
    int row0 = (bx & 255) * 16;
    for (int i = tid; i < 4096; i += 256) { int r = i >> 6, c = i & 63; Wl[r*65+c] = W[i]; }
    for (int i = tid; i < 1024; i += 256) { int r = i >> 6, c = i & 63; inl[r*65+c] = in[(row0+r)*64 + c]; }
    if (tid < 64) bl[tid] = b[tid];
    __syncthreads();

    int col = tid & 63;
    int rq  = tid >> 6;
    #pragma unroll
    for (int q = 0; q < 4; ++q) {
        int r = rq*4 + q;
        float acc = bl[col];
        #pragma unroll
        for (int k = 0; k < 64; ++k) acc += inl[r*65+k] * Wl[col*65+k];
        float t = tanhf(acc);
        f16 h = (f16)t;
        oh[(row0+r)*64 + col] = h;
        if (ol) {
            float lo = t - (float)h;
            if (scaled) lo *= 2048.0f;
            ol[(row0+r)*64 + col] = (f16)lo;
        }
    }
}

// ---------------- sim = kp @ mem_keys.T via f16-split MFMA (3-term); partial argmax ----------------
// grid (32 sb x 1024 slots, 16 rb x 256 rows); block 256 = 4 waves x 64 rows
__global__ __launch_bounds__(256, 2) void sim_kernel(
    const f16* __restrict__ Aph, const f16* __restrict__ Apl,
    const f16* __restrict__ Bph, const f16* __restrict__ Bpl,
    float* __restrict__ bestv, int* __restrict__ besti)
{
    __shared__ __align__(16) f16 Bh[64*72], Bl[64*72];
    int tid = threadIdx.x, l = tid & 63, w = tid >> 6;
    int sb = blockIdx.x, rb = blockIdx.y;
    int row0 = rb*256 + w*64;
    int lr = l & 15, lg = l >> 4;
    int sl0 = tid >> 3, ch = tid & 7;

    f16x8 ah[4][2], al[4][2];
    #pragma unroll
    for (int i = 0; i < 4; ++i)
        #pragma unroll
        for (int t = 0; t < 2; ++t) {
            size_t o = (size_t)(row0 + i*16 + lr)*64 + t*32 + lg*8;
            ah[i][t] = *(const f16x8*)&Aph[o];
            al[i][t] = *(const f16x8*)&Apl[o];
        }
    float bvv[4][4]; int bii[4][4];
    #pragma unroll
    for (int i = 0; i < 4; ++i)
        #pragma unroll
        for (int j = 0; j < 4; ++j) { bvv[i][j] = -FLT_MAX; bii[i][j] = 0; }

    f16x8 pb[2][2];
    {
        int s0 = sb*1024;
        pb[0][0] = *(const f16x8*)&Bph[(size_t)(s0+sl0)*64 + ch*8];
        pb[0][1] = *(const f16x8*)&Bpl[(size_t)(s0+sl0)*64 + ch*8];
        pb[1][0] = *(const f16x8*)&Bph[(size_t)(s0+sl0+32)*64 + ch*8];
        pb[1][1] = *(const f16x8*)&Bpl[(size_t)(s0+sl0+32)*64 + ch*8];
    }

    for (int st = 0; st < 16; ++st) {
        int s0 = sb*1024 + st*64;
        __syncthreads();
        *(f16x8*)&Bh[sl0*72 + ch*8]      = pb[0][0];
        *(f16x8*)&Bl[sl0*72 + ch*8]      = pb[0][1];
        *(f16x8*)&Bh[(sl0+32)*72 + ch*8] = pb[1][0];
        *(f16x8*)&Bl[(sl0+32)*72 + ch*8] = pb[1][1];
        __syncthreads();
        if (st + 1 < 16) {
            int sn = s0 + 64;
            pb[0][0] = *(const f16x8*)&Bph[(size_t)(sn+sl0)*64 + ch*8];
            pb[0][1] = *(const f16x8*)&Bpl[(size_t)(sn+sl0)*64 + ch*8];
            pb[1][0] = *(const f16x8*)&Bph[(size_t)(sn+sl0+32)*64 + ch*8];
            pb[1][1] = *(const f16x8*)&Bpl[(size_t)(sn+sl0+32)*64 + ch*8];
        }
        #pragma unroll
        for (int cf = 0; cf < 4; ++cf) {
            int c0 = cf*16;
            f16x8 bh[2], bl2[2];
            #pragma unroll
            for (int t = 0; t < 2; ++t) {
                bh[t]  = *(const f16x8*)&Bh[(c0+lr)*72 + t*32 + lg*8];
                bl2[t] = *(const f16x8*)&Bl[(c0+lr)*72 + t*32 + lg*8];
            }
            f32x4 z = {0.f,0.f,0.f,0.f};
            f32x4 aA[4] = {z,z,z,z}, aB[4] = {z,z,z,z};
            #pragma unroll
            for (int i = 0; i < 4; ++i)
                #pragma unroll
                for (int t = 0; t < 2; ++t) {
                    aA[i] = MF(ah[i][t], bh[t],  aA[i]);
                    aB[i] = MF(ah[i][t], bl2[t], aB[i]);
                    aB[i] = MF(al[i][t], bh[t],  aB[i]);
                }
            int slot = s0 + c0 + lr;
            #pragma unroll
            for (int i = 0; i < 4; ++i)
                #pragma unroll
                for (int j = 0; j < 4; ++j) {
                    float v = aA[i][j] + aB[i][j]*(1.0f/2048.0f);
                    if (v > bvv[i][j]) { bvv[i][j] = v; bii[i][j] = slot; }
                }
        }
    }
    #pragma unroll
    for (int m = 1; m < 16; m <<= 1)
        #pragma unroll
        for (int i = 0; i < 4; ++i)
            #pragma unroll
            for (int j = 0; j < 4; ++j) {
                float ov = __shfl_xor(bvv[i][j], m);
                int   oi = __shfl_xor(bii[i][j], m);
                if (ov > bvv[i][j] || (ov == bvv[i][j] && oi < bii[i][j])) { bvv[i][j] = ov; bii[i][j] = oi; }
            }
    if (lr == 0) {
        #pragma unroll
        for (int i = 0; i < 4; ++i)
            #pragma unroll
            for (int j = 0; j < 4; ++j) {
                int r = row0 + i*16 + lg*4 + j;
                bestv[r*32 + sb] = bvv[i][j];
                besti[r*32 + sb] = bii[i][j];
            }
    }
}

// ---------------- argmax combine + winner scatter ----------------
__global__ void argmax_scatter_kernel(const float* __restrict__ bestv,
                                      const int* __restrict__ besti,
                                      int* __restrict__ winner)
{
    int r = blockIdx.x*256 + threadIdx.x;
    if (r >= BATCH) return;
    float bv = bestv[r*32]; int bi = besti[r*32];
    #pragma unroll
    for (int sb = 1; sb < 32; ++sb) {
        float v = bestv[r*32+sb]; int ii = besti[r*32+sb];
        if (v > bv || (v == bv && ii < bi)) { bv = v; bi = ii; }
    }
    atomicMax(&winner[bi], r);
}

// ---------------- build new_keys planes + transposed new_values (hi only) ----------------
__global__ __launch_bounds__(256) void build_kernel(
    const int* __restrict__ winner,
    const f16* __restrict__ kph, const f16* __restrict__ kpl,
    const f16* __restrict__ svh,
    const float* __restrict__ mk, const float* __restrict__ mv,
    f16* __restrict__ nkh, f16* __restrict__ nkl,
    f16* __restrict__ nvTh)
{
    __shared__ __align__(16) f16 Lh[64*72];
    int tid = threadIdx.x;
    int s0 = blockIdx.x*64;
    #pragma unroll
    for (int c = 0; c < 2; ++c) {
        int task = tid + 256*c; int sl = task >> 3, ch = task & 7;
        int s = s0 + sl; int w = winner[s];
        f16x8 hk, lk, hv;
        if (w >= 0) {
            hk = *(const f16x8*)&kph[(size_t)w*64 + ch*8];
            f16x8 lraw = *(const f16x8*)&kpl[(size_t)w*64 + ch*8];
            #pragma unroll
            for (int q = 0; q < 8; ++q) lk[q] = (f16)((float)lraw[q] * (1.0f/2048.0f));
            hv = *(const f16x8*)&svh[(size_t)w*64 + ch*8];
        } else {
            #pragma unroll
            for (int q = 0; q < 8; ++q) {
                float x = mk[(size_t)s*64 + ch*8 + q];
                f16 h = (f16)x; hk[q] = h; lk[q] = (f16)(x - (float)h);
                float y = mv[(size_t)s*64 + ch*8 + q];
                hv[q] = (f16)y;
            }
        }
        *(f16x8*)&nkh[(size_t)s*64 + ch*8] = hk;
        *(f16x8*)&nkl[(size_t)s*64 + ch*8] = lk;
        *(f16x8*)&Lh[sl*72 + ch*8] = hv;
    }
    __syncthreads();
    int v = tid >> 2, sc = (tid & 3)*16;
    f16x8 a, b2;
    #pragma unroll
    for (int q = 0; q < 8; ++q) { a[q] = Lh[(sc+q)*72 + v]; b2[q] = Lh[(sc+8+q)*72 + v]; }
    *(f16x8*)&nvTh[(size_t)v*CAP + s0 + sc]     = a;
    *(f16x8*)&nvTh[(size_t)v*CAP + s0 + sc + 8] = b2;
}

// ---------------- pass1: denominator only. hh-only logits; S = sum exp(v) (no max shift) ----------------
// grid (64 sb x 512 slots, 8 rb x 512 rows); block 256 = 4 waves x 128 rows
__global__ __launch_bounds__(256, 2) void logits_stats_kernel(
    const f16* __restrict__ Aph,
    const f16* __restrict__ Bph,
    float* __restrict__ s_part)
{
    __shared__ __align__(16) f16 Bh[64*72];
    int tid = threadIdx.x, l = tid & 63, w = tid >> 6;
    int sb = blockIdx.x, rb = blockIdx.y;
    int row0 = rb*512 + w*128;
    int lr = l & 15, lg = l >> 4;
    int sl0 = tid >> 3, ch = tid & 7;

    f16x8 ah[8][2];
    #pragma unroll
    for (int i = 0; i < 8; ++i)
        #pragma unroll
        for (int t = 0; t < 2; ++t)
            ah[i][t] = *(const f16x8*)&Aph[(size_t)(row0 + i*16 + lr)*64 + t*32 + lg*8];

    float ssum[8][4];
    #pragma unroll
    for (int i = 0; i < 8; ++i)
        #pragma unroll
        for (int j = 0; j < 4; ++j) ssum[i][j] = 0.f;

    f16x8 pb[2];
    {
        int s0 = sb*512;
        pb[0] = *(const f16x8*)&Bph[(size_t)(s0+sl0)*64 + ch*8];
        pb[1] = *(const f16x8*)&Bph[(size_t)(s0+sl0+32)*64 + ch*8];
    }

    for (int st = 0; st < 8; ++st) {
        int s0 = sb*512 + st*64;
        __syncthreads();
        *(f16x8*)&Bh[sl0*72 + ch*8]      = pb[0];
        *(f16x8*)&Bh[(sl0+32)*72 + ch*8] = pb[1];
        __syncthreads();
        if (st + 1 < 8) {
            int sn = s0 + 64;
            pb[0] = *(const f16x8*)&Bph[(size_t)(sn+sl0)*64 + ch*8];
            pb[1] = *(const f16x8*)&Bph[(size_t)(sn+sl0+32)*64 + ch*8];
        }
        #pragma unroll
        for (int cf = 0; cf < 4; ++cf) {
            int c0 = cf*16;
            f16x8 bh[2];
            #pragma unroll
            for (int t = 0; t < 2; ++t)
                bh[t] = *(const f16x8*)&Bh[(c0+lr)*72 + t*32 + lg*8];
            f32x4 z = {0.f,0.f,0.f,0.f};
            f32x4 acc[8] = {z,z,z,z,z,z,z,z};
            #pragma unroll
            for (int i = 0; i < 8; ++i) {
                acc[i] = MF(ah[i][0], bh[0], acc[i]);
                acc[i] = MF(ah[i][1], bh[1], acc[i]);
            }
            #pragma unroll
            for (int i = 0; i < 8; ++i)
                #pragma unroll
                for (int j = 0; j < 4; ++j)
                    ssum[i][j] += __expf(acc[i][j]);
        }
    }
    #pragma unroll
    for (int m = 1; m < 16; m <<= 1)
        #pragma unroll
        for (int i = 0; i < 8; ++i)
            #pragma unroll
            for (int j = 0; j < 4; ++j)
                ssum[i][j] += __shfl_xor(ssum[i][j], m);
    if (lr == 0) {
        #pragma unroll
        for (int i = 0; i < 8; ++i)
            #pragma unroll
            for (int j = 0; j < 4; ++j) {
                int r = row0 + i*16 + lg*4 + j;
                s_part[r*64 + sb] = ssum[i][j];
            }
    }
}

// ---------------- combine per-row denominator ----------------
__global__ void stats_combine_kernel(const float* __restrict__ s_part,
                                     float* __restrict__ iSrow)
{
    int r = blockIdx.x*256 + threadIdx.x;
    if (r >= BATCH) return;
    const float4* p = (const float4*)(s_part + r*64);
    float S = 0.f;
    #pragma unroll
    for (int q = 0; q < 16; ++q) {
        float4 v = p[q];
        S += (v.x + v.y) + (v.z + v.w);
    }
    iSrow[r] = 1.f/S;
}

// ---------------- pass2: recompute logits (3-term), att = exp(v)*iS, fused PV (1-term) ----------------
// grid (16 sb x 2048 slots, 32 rb x 128 rows); block 256 = 4 waves (2 wr x 2 wc)
__global__ __launch_bounds__(256, 2) void pass2_kernel(
    const f16* __restrict__ qph, const f16* __restrict__ qpl,
    const f16* __restrict__ nkh, const f16* __restrict__ nkl,
    const f16* __restrict__ nvTh,
    const float* __restrict__ iSrow,
    float* __restrict__ att, float* __restrict__ ret_part)
{
    __shared__ __align__(16) f16 Kh[64*72], Kl[64*72];
    __shared__ __align__(16) f16 Vh[64*72];
    __shared__ __align__(16) f16 Ph[128*72];
    int tid = threadIdx.x, l = tid & 63, w = tid >> 6;
    int wr = w >> 1, wc = w & 1;
    int sb = blockIdx.x, rb = blockIdx.y;
    int wrow0 = rb*128 + wr*64;
    int lr = l & 15, lg = l >> 4;
    int sl0 = tid >> 3, ch = tid & 7;

    f16x8 ah[4][2], al[4][2];
    #pragma unroll
    for (int i = 0; i < 4; ++i)
        #pragma unroll
        for (int t = 0; t < 2; ++t) {
            size_t o = (size_t)(wrow0 + i*16 + lr)*64 + t*32 + lg*8;
            ah[i][t] = *(const f16x8*)&qph[o];
            al[i][t] = *(const f16x8*)&qpl[o];
        }
    float iS[4][4];
    #pragma unroll
    for (int i = 0; i < 4; ++i)
        #pragma unroll
        for (int j = 0; j < 4; ++j)
            iS[i][j] = iSrow[wrow0 + i*16 + lg*4 + j];

    f32x4 z = {0.f,0.f,0.f,0.f};
    f32x4 pacc[4][2] = {{z,z},{z,z},{z,z},{z,z}};

    f16x8 pk[2][2], pv[2];
    {
        int s0g = sb*2048;
        pk[0][0] = *(const f16x8*)&nkh[(size_t)(s0g+sl0)*64 + ch*8];
        pk[0][1] = *(const f16x8*)&nkl[(size_t)(s0g+sl0)*64 + ch*8];
        pk[1][0] = *(const f16x8*)&nkh[(size_t)(s0g+sl0+32)*64 + ch*8];
        pk[1][1] = *(const f16x8*)&nkl[(size_t)(s0g+sl0+32)*64 + ch*8];
        pv[0]    = *(const f16x8*)&nvTh[(size_t)sl0*CAP + s0g + ch*8];
        pv[1]    = *(const f16x8*)&nvTh[(size_t)(sl0+32)*CAP + s0g + ch*8];
    }

    for (int st = 0; st < 32; ++st) {
        int s0g = sb*2048 + st*64;
        __syncthreads();
        *(f16x8*)&Kh[sl0*72 + ch*8]      = pk[0][0];
        *(f16x8*)&Kl[sl0*72 + ch*8]      = pk[0][1];
        *(f16x8*)&Kh[(sl0+32)*72 + ch*8] = pk[1][0];
        *(f16x8*)&Kl[(sl0+32)*72 + ch*8] = pk[1][1];
        *(f16x8*)&Vh[sl0*72 + ch*8]      = pv[0];
        *(f16x8*)&Vh[(sl0+32)*72 + ch*8] = pv[1];
        __syncthreads();
        if (st + 1 < 32) {
            int sn = s0g + 64;
            pk[0][0] = *(const f16x8*)&nkh[(size_t)(sn+sl0)*64 + ch*8];
            pk[0][1] = *(const f16x8*)&nkl[(size_t)(sn+sl0)*64 + ch*8];
            pk[1][0] = *(const f16x8*)&nkh[(size_t)(sn+sl0+32)*64 + ch*8];
            pk[1][1] = *(const f16x8*)&nkl[(size_t)(sn+sl0+32)*64 + ch*8];
            pv[0]    = *(const f16x8*)&nvTh[(size_t)sl0*CAP + sn + ch*8];
            pv[1]    = *(const f16x8*)&nvTh[(size_t)(sl0+32)*CAP + sn + ch*8];
        }
        // QK^T (3-term) + att write + P to LDS
        #pragma unroll
        for (int cf = 0; cf < 2; ++cf) {
            int c0 = wc*32 + cf*16;
            f16x8 bh[2], bl2[2];
            #pragma unroll
            for (int t = 0; t < 2; ++t) {
                bh[t]  = *(const f16x8*)&Kh[(c0+lr)*72 + t*32 + lg*8];
                bl2[t] = *(const f16x8*)&Kl[(c0+lr)*72 + t*32 + lg*8];
            }
            f32x4 qacc[4] = {z,z,z,z};
            #pragma unroll
            for (int i = 0; i < 4; ++i)
                #pragma unroll
                for (int t = 0; t < 2; ++t) {
                    qacc[i] = MF(ah[i][t], bh[t],  qacc[i]);
                    qacc[i] = MF(ah[i][t], bl2[t], qacc[i]);
                    qacc[i] = MF(al[i][t], bh[t],  qacc[i]);
                }
            #pragma unroll
            for (int i = 0; i < 4; ++i)
                #pragma unroll
                for (int j = 0; j < 4; ++j) {
                    float a = __expf(qacc[i][j]) * iS[i][j];
                    int gr = wrow0 + i*16 + lg*4 + j;
                    att[(size_t)gr*CAP + s0g + c0 + lr] = a;
                    Ph[(wr*64 + i*16 + lg*4 + j)*72 + c0 + lr] = (f16)a;
                }
        }
        __syncthreads();   // P visible
        // PV (1-term)
        f16x8 pah[4][2];
        #pragma unroll
        for (int i = 0; i < 4; ++i)
            #pragma unroll
            for (int t = 0; t < 2; ++t)
                pah[i][t] = *(const f16x8*)&Ph[(wr*64 + i*16 + lr)*72 + t*32 + lg*8];
        #pragma unroll
        for (int vf = 0; vf < 2; ++vf) {
            f16x8 vbh[2];
            #pragma unroll
            for (int t = 0; t < 2; ++t)
                vbh[t] = *(const f16x8*)&Vh[(wc*32 + vf*16 + lr)*72 + t*32 + lg*8];
            #pragma unroll
            for (int i = 0; i < 4; ++i)
                #pragma unroll
                for (int t = 0; t < 2; ++t)
                    pacc[i][vf] = MF(pah[i][t], vbh[t], pacc[i][vf]);
        }
    }
    #pragma unroll
    for (int i = 0; i < 4; ++i)
        #pragma unroll
        for (int vf = 0; vf < 2; ++vf)
            #pragma unroll
            for (int j = 0; j < 4; ++j) {
                int gr = wrow0 + i*16 + lg*4 + j;
                int gc = wc*32 + vf*16 + lr;
                ret_part[((size_t)sb*BATCH + gr)*64 + gc] = pacc[i][vf][j];
            }
}

// ---------------- reduce partial retrieved ----------------
__global__ void ret_reduce_kernel(const float* __restrict__ rp, float* __restrict__ out)
{
    int i4 = blockIdx.x*256 + threadIdx.x;   // BATCH*64/4 = 65536
    float4 s = {0.f,0.f,0.f,0.f};
    #pragma unroll
    for (int sb = 0; sb < 16; ++sb) {
        float4 p = ((const float4*)(rp + (size_t)sb*BATCH*64))[i4];
        s.x += p.x; s.y += p.y; s.z += p.z; s.w += p.w;
    }
    ((float4*)out)[i4] = s;
}

extern "C" void kernel_launch(void* const* d_in, const int* in_sizes, int n_in,
                              void* d_out, int out_size, void* d_ws, size_t ws_size,
                              hipStream_t stream) {
    const float* keys       = (const float*)d_in[0];
    const float* query      = (const float*)d_in[2];
    const float* mem_keys   = (const float*)d_in[3];
    const float* mem_values = (const float*)d_in[4];
    const float* Wk         = (const float*)d_in[5];
    const float* bk         = (const float*)d_in[6];
    const float* Wv         = (const float*)d_in[7];
    const float* bv         = (const float*)d_in[8];

    float* out = (float*)d_out;
    float* ret = out;                       // [4096,64]
    float* att = out + BATCH*64;            // [4096,32768]

    char* ws = (char*)d_ws;
    const size_t SK = (size_t)BATCH*64*2;   // 512 KB  f16 plane [4096][64]
    const size_t SC = (size_t)CAP*64*2;     // 4 MB    f16 plane [32768][64]
    f16* kph  = (f16*)(ws + 0*SK);
    f16* kpl  = (f16*)(ws + 1*SK);
    f16* svh  = (f16*)(ws + 2*SK);
    f16* qph  = (f16*)(ws + 3*SK);
    f16* qpl  = (f16*)(ws + 4*SK);
    size_t o = 5*SK;
    f16* nkh  = (f16*)(ws + o);            o += SC;
    f16* nkl  = (f16*)(ws + o);            o += SC;
    f16* nvTh = (f16*)(ws + o);            o += SC;
    float* bestv  = (float*)(ws + o);      o += (size_t)BATCH*32*4;
    int*   besti  = (int*)(ws + o);        o += (size_t)BATCH*32*4;
    float* s_part = (float*)(ws + o);      o += (size_t)BATCH*64*4;
    float* iSrow  = (float*)(ws + o);      o += (size_t)BATCH*4;
    int*   winner = (int*)(ws + o);        o += (size_t)CAP*4;
    float* ret_part = (float*)(ws + o);    // 16*4096*64*4 = 16.8 MB
    // mk planes overlaid on ret_part (disjoint lifetimes: sim vs pass2)
    f16* mkh = (f16*)ret_part;
    f16* mkl = (f16*)((char*)ret_part + SC);

    prep_kernel<<<768 + CAP*64/256, 256, 0, stream>>>(
        keys, query, Wk, bk, Wv, bv, mem_keys,
        kph, kpl, svh, qph, qpl, mkh, mkl, winner);
    sim_kernel<<<dim3(32, 16), 256, 0, stream>>>(kph, kpl, mkh, mkl, bestv, besti);
    argmax_scatter_kernel<<<BATCH/256, 256, 0, stream>>>(bestv, besti, winner);
    build_kernel<<<CAP/64, 256, 0, stream>>>(
        winner, kph, kpl, svh, mem_keys, mem_values, nkh, nkl, nvTh);
    logits_stats_kernel<<<dim3(64, 8), 256, 0, stream>>>(qph, nkh, s_part);
    stats_combine_kernel<<<BATCH/256, 256, 0, stream>>>(s_part, iSrow);
    pass2_kernel<<<dim3(16, 32), 256, 0, stream>>>(
        qph, qpl, nkh, nkl, nvTh, iSrow, att, ret_part);
    ret_reduce_kernel<<<BATCH*64/4/256, 256, 0, stream>>>(ret_part, ret);
}